// Round 7
// baseline (56.371 us; speedup 1.0000x reference)
//
#include <hip/hip_runtime.h>

// SymmetricContraction (MACE-style), B=128, C=128, E=10, L=16.
// Collapsed to GEMM + Q-fold:
//   D[m,p] = sum_kappa A[m,kappa] * Bm[kappa,p]
//     A1 = U3_1o as [768][528] ++ U2_1o cols (K=544 padded)
//     A0 = U3_0e as [256][368] ++ U2_0e cols (K=384 padded)
//     Bm[kappa=(i,k), p] = x[i,p] * z3[k,p]; U2 cols = z2[k,p]; pad = 0
//   out[group,p] = sum_m Q[m,p]*D[m,p] + z1*U1-term,  Q = x[qa,p]*x[qb,p]
// z*[k,p] = sum_e w*[e][k][c]*y[b][e]  (p = b*128+c)
//
// Round 7: round 6 was occupancy-starved (144KB LDS -> 1 blk/CU, 2 waves/SIMD).
// Now 768-thr blocks (12 waves -> 3 waves/SIMD), typed blocks:
//   blk <  256: 1o, 64 pairs, wave wv owns 64 rows (acc[4][4], 64 VGPR)
//   blk >= 256: 0e, 64 pairs, waves 0..7 own 32 rows (acc[2][4]); waves 8..11
//               help staging only.
// LDS union ~88KB (B built ONCE, f32 zbuf, no barriers in MFMA loop).
// A read directly from f32 U and packed to bf16 via v_cvt_pk_bf16_f32
// (single kernel -- no ws handoff, replay-safe as round 6).

typedef float  f32x4  __attribute__((ext_vector_type(4)));
typedef short  short8 __attribute__((ext_vector_type(8)));

namespace {
constexpr int EE = 10;

struct Sh1 {
  unsigned short B1[64][552];  // 70656 B (cols 0..543 used)
  float x[16][64];             //  4096 B
  float z[40][64];             // 10240 B: 0..32 z3, 33..38 z2, 39 z1
  float red[12][64];           //  3072 B
};
struct Sh0 {
  unsigned short B0[64][392];  // 50176 B (cols 0..383 used)
  float x[16][64];
  float z[28][64];             // 0..22 z3, 23..26 z2, 27 z1
  float red[8][64];
};
union ShU { Sh1 o1; Sh0 o0; };
}

__device__ __forceinline__ unsigned cvtpk(float lo, float hi) {
  unsigned r;
  asm("v_cvt_pk_bf16_f32 %0, %1, %2" : "=v"(r) : "v"(lo), "v"(hi));
  return r;
}

__device__ __forceinline__ short8 pack8(float f0, float f1, float f2, float f3,
                                        float f4, float f5, float f6, float f7) {
  union { short8 s; unsigned u[4]; } r;
  r.u[0] = cvtpk(f0, f1);
  r.u[1] = cvtpk(f2, f3);
  r.u[2] = cvtpk(f4, f5);
  r.u[3] = cvtpk(f6, f7);
  return r.s;
}

__global__ __launch_bounds__(768) void symcon_mfma(
    const float* __restrict__ x,      // [B][C][16]
    const float* __restrict__ y,      // [B][E]
    const float* __restrict__ U1_0e,  // [16]
    const float* __restrict__ U2_0e,  // [256][4]
    const float* __restrict__ U3_0e,  // [256][368]
    const float* __restrict__ U1_1o,  // [3][16]
    const float* __restrict__ U2_1o,  // [768][6]
    const float* __restrict__ U3_1o,  // [768][528]
    const float* __restrict__ w1_0e, const float* __restrict__ w2_0e,
    const float* __restrict__ w3_0e, const float* __restrict__ w1_1o,
    const float* __restrict__ w2_1o, const float* __restrict__ w3_1o,
    float* __restrict__ out)          // [B][512]
{
  __shared__ ShU sh;

  const int tid   = threadIdx.x;
  const int blk   = blockIdx.x;          // 0..511
  const bool is1o = (blk < 256);
  const int pblk  = is1o ? blk : blk - 256;
  const int pair0 = pblk * 64;
  const int b     = pblk >> 1;           // uniform
  const int lane  = tid & 63;
  const int wv    = tid >> 6;            // 0..11
  const int lrow  = lane & 15;
  const int lgr   = lane >> 4;

  if (is1o) {
    // ================= 1o block =================
    // ---- stage x ----
    for (int t = tid; t < 16 * 64; t += 768) {
      const int i = t >> 6, n = t & 63;
      sh.o1.x[i][n] = x[(size_t)(pair0 + n) * 16 + i];
    }
    // ---- stage z (40 rows f32) ----
    for (int t = tid; t < 40 * 64; t += 768) {
      const int n  = t & 63;
      const int zi = t >> 6;
      const int c  = ((pblk & 1) << 6) + n;
      const float* yb = y + b * EE;
      const float* wsrc; int stride;
      if      (zi < 33) { wsrc = w3_1o + zi * 128 + c;        stride = 33 * 128; }
      else if (zi < 39) { wsrc = w2_1o + (zi - 33) * 128 + c; stride =  6 * 128; }
      else              { wsrc = w1_1o + c;                   stride =      128; }
      float a = 0.f;
      #pragma unroll
      for (int e = 0; e < EE; ++e) a += wsrc[e * stride] * yb[e];
      sh.o1.z[zi][n] = a;
    }
    __syncthreads();

    // ---- build B1 once (kappa pairs -> u32) ----
    #pragma unroll 1
    for (int idx = tid; idx < 272 * 64; idx += 768) {
      const int p = idx & 63, cp = idx >> 6;
      const int k0 = cp * 2;
      float v0, v1;
      if (k0 < 528) {
        const int i = k0 / 33, kk = k0 - i * 33;
        v0 = sh.o1.x[i][p] * sh.o1.z[kk][p];
        const int k1 = k0 + 1;
        const int i1 = k1 / 33, kk1 = k1 - i1 * 33;
        v1 = sh.o1.x[i1][p] * sh.o1.z[kk1][p];
      } else if (k0 < 534) {
        v0 = sh.o1.z[33 + (k0 - 528)][p];
        v1 = (k0 + 1 < 534) ? sh.o1.z[33 + (k0 - 527)][p] : 0.f;
      } else {
        v0 = 0.f; v1 = 0.f;
      }
      *(unsigned*)&sh.o1.B1[p][k0] = cvtpk(v0, v1);
    }
    __syncthreads();

    // ---- MFMA: wave wv owns rows [wv*64, wv*64+64) ----
    const int mbase = wv * 64;
    const float* __restrict__ U3r[4];
    #pragma unroll
    for (int mf = 0; mf < 4; ++mf)
      U3r[mf] = U3_1o + (size_t)(mbase + mf * 16 + lrow) * 528 + lgr * 8;

    f32x4 acc[4][4] = {};

    #pragma unroll 2
    for (int t = 0; t < 16; ++t) {
      short8 af[4];
      #pragma unroll
      for (int mf = 0; mf < 4; ++mf) {
        f32x4 a  = *(const f32x4*)(U3r[mf] + t * 32);
        f32x4 bq = *(const f32x4*)(U3r[mf] + t * 32 + 4);
        af[mf] = pack8(a[0], a[1], a[2], a[3], bq[0], bq[1], bq[2], bq[3]);
      }
      short8 bfr[4];
      #pragma unroll
      for (int nf = 0; nf < 4; ++nf)
        bfr[nf] = *(const short8*)&sh.o1.B1[nf * 16 + lrow][t * 32 + lgr * 8];
      #pragma unroll
      for (int mf = 0; mf < 4; ++mf)
        #pragma unroll
        for (int nf = 0; nf < 4; ++nf)
          acc[mf][nf] = __builtin_amdgcn_mfma_f32_16x16x32_bf16(af[mf], bfr[nf], acc[mf][nf], 0, 0, 0);
    }
    {   // tail t=16: kappa 512..543 = U3 512..527 | U2[0..5] | zeros
      short8 af[4];
      #pragma unroll
      for (int mf = 0; mf < 4; ++mf) {
        const int row = mbase + mf * 16 + lrow;
        if (lgr < 2) {
          const float* p = U3_1o + (size_t)row * 528 + 512 + lgr * 8;
          f32x4 a = *(const f32x4*)p; f32x4 bq = *(const f32x4*)(p + 4);
          af[mf] = pack8(a[0], a[1], a[2], a[3], bq[0], bq[1], bq[2], bq[3]);
        } else if (lgr == 2) {
          const float* p = U2_1o + row * 6;
          af[mf] = pack8(p[0], p[1], p[2], p[3], p[4], p[5], 0.f, 0.f);
        } else {
          af[mf] = short8{0, 0, 0, 0, 0, 0, 0, 0};
        }
      }
      short8 bfr[4];
      #pragma unroll
      for (int nf = 0; nf < 4; ++nf)
        bfr[nf] = *(const short8*)&sh.o1.B1[nf * 16 + lrow][512 + lgr * 8];
      #pragma unroll
      for (int mf = 0; mf < 4; ++mf)
        #pragma unroll
        for (int nf = 0; nf < 4; ++nf)
          acc[mf][nf] = __builtin_amdgcn_mfma_f32_16x16x32_bf16(af[mf], bfr[nf], acc[mf][nf], 0, 0, 0);
    }

    // ---- epilogue: Q-fold + reduce ----
    float s[4] = {0.f, 0.f, 0.f, 0.f};
    const int rg = lgr * 4;
    #pragma unroll
    for (int mf = 0; mf < 4; ++mf) {
      #pragma unroll
      for (int reg = 0; reg < 4; ++reg) {
        const int q  = (mbase + mf * 16 + rg + reg) & 255;  // row % 256
        const int qa = q >> 4, qb = q & 15;
        #pragma unroll
        for (int nf = 0; nf < 4; ++nf) {
          const int p = nf * 16 + lrow;
          s[nf] += acc[mf][nf][reg] * (sh.o1.x[qa][p] * sh.o1.x[qb][p]);
        }
      }
    }
    #pragma unroll
    for (int nf = 0; nf < 4; ++nf) {
      s[nf] += __shfl_xor(s[nf], 16);
      s[nf] += __shfl_xor(s[nf], 32);
    }
    if (lane < 16) {
      #pragma unroll
      for (int nf = 0; nf < 4; ++nf) sh.o1.red[wv][nf * 16 + lane] = s[nf];
    }
    __syncthreads();

    // ---- combine + U1 term (w = wv>>2 -> red rows 4w..4w+3) ----
    if (tid < 192) {
      const int slot = tid >> 6;   // w = 0..2
      const int n    = tid & 63;
      const int cc   = ((pblk & 1) << 6) + n;
      float v = sh.o1.red[4 * slot][n] + sh.o1.red[4 * slot + 1][n]
              + sh.o1.red[4 * slot + 2][n] + sh.o1.red[4 * slot + 3][n];
      float u1 = 0.f;
      #pragma unroll
      for (int xx = 0; xx < 16; ++xx) u1 += U1_1o[slot * 16 + xx] * sh.o1.x[xx][n];
      out[(size_t)b * 512 + 128 + cc * 3 + slot] = v + sh.o1.z[39][n] * u1;
    }
  } else {
    // ================= 0e block =================
    for (int t = tid; t < 16 * 64; t += 768) {
      const int i = t >> 6, n = t & 63;
      sh.o0.x[i][n] = x[(size_t)(pair0 + n) * 16 + i];
    }
    for (int t = tid; t < 28 * 64; t += 768) {
      const int n  = t & 63;
      const int zi = t >> 6;
      const int c  = ((pblk & 1) << 6) + n;
      const float* yb = y + b * EE;
      const float* wsrc; int stride;
      if      (zi < 23) { wsrc = w3_0e + zi * 128 + c;        stride = 23 * 128; }
      else if (zi < 27) { wsrc = w2_0e + (zi - 23) * 128 + c; stride =  4 * 128; }
      else              { wsrc = w1_0e + c;                   stride =      128; }
      float a = 0.f;
      #pragma unroll
      for (int e = 0; e < EE; ++e) a += wsrc[e * stride] * yb[e];
      sh.o0.z[zi][n] = a;
    }
    __syncthreads();

    #pragma unroll 1
    for (int idx = tid; idx < 192 * 64; idx += 768) {
      const int p = idx & 63, cp = idx >> 6;
      const int k0 = cp * 2;
      float v0, v1;
      if (k0 < 368) {
        const int i = k0 / 23, kk = k0 - i * 23;
        v0 = sh.o0.x[i][p] * sh.o0.z[kk][p];
        const int k1 = k0 + 1;
        const int i1 = k1 / 23, kk1 = k1 - i1 * 23;
        v1 = sh.o0.x[i1][p] * sh.o0.z[kk1][p];
      } else if (k0 < 372) {
        v0 = sh.o0.z[23 + (k0 - 368)][p];
        v1 = (k0 + 1 < 372) ? sh.o0.z[23 + (k0 - 367)][p] : 0.f;
      } else {
        v0 = 0.f; v1 = 0.f;
      }
      *(unsigned*)&sh.o0.B0[p][k0] = cvtpk(v0, v1);
    }
    __syncthreads();

    if (wv < 8) {
      // ---- MFMA: wave wv owns rows [wv*32, wv*32+32) ----
      const int mbase = wv * 32;
      const float* __restrict__ U3r[2];
      #pragma unroll
      for (int mf = 0; mf < 2; ++mf)
        U3r[mf] = U3_0e + (size_t)(mbase + mf * 16 + lrow) * 368 + lgr * 8;

      f32x4 acc[2][4] = {};

      #pragma unroll 2
      for (int t = 0; t < 11; ++t) {
        short8 af[2];
        #pragma unroll
        for (int mf = 0; mf < 2; ++mf) {
          f32x4 a  = *(const f32x4*)(U3r[mf] + t * 32);
          f32x4 bq = *(const f32x4*)(U3r[mf] + t * 32 + 4);
          af[mf] = pack8(a[0], a[1], a[2], a[3], bq[0], bq[1], bq[2], bq[3]);
        }
        short8 bfr[4];
        #pragma unroll
        for (int nf = 0; nf < 4; ++nf)
          bfr[nf] = *(const short8*)&sh.o0.B0[nf * 16 + lrow][t * 32 + lgr * 8];
        #pragma unroll
        for (int mf = 0; mf < 2; ++mf)
          #pragma unroll
          for (int nf = 0; nf < 4; ++nf)
            acc[mf][nf] = __builtin_amdgcn_mfma_f32_16x16x32_bf16(af[mf], bfr[nf], acc[mf][nf], 0, 0, 0);
      }
      {   // tail t=11: kappa 352..383 = U3 352..367 | U2[0..3] | zeros
        short8 af[2];
        #pragma unroll
        for (int mf = 0; mf < 2; ++mf) {
          const int row = mbase + mf * 16 + lrow;
          if (lgr < 2) {
            const float* p = U3_0e + (size_t)row * 368 + 352 + lgr * 8;
            f32x4 a = *(const f32x4*)p; f32x4 bq = *(const f32x4*)(p + 4);
            af[mf] = pack8(a[0], a[1], a[2], a[3], bq[0], bq[1], bq[2], bq[3]);
          } else if (lgr == 2) {
            const float* p = U2_0e + row * 4;
            af[mf] = pack8(p[0], p[1], p[2], p[3], 0.f, 0.f, 0.f, 0.f);
          } else {
            af[mf] = short8{0, 0, 0, 0, 0, 0, 0, 0};
          }
        }
        short8 bfr[4];
        #pragma unroll
        for (int nf = 0; nf < 4; ++nf)
          bfr[nf] = *(const short8*)&sh.o0.B0[nf * 16 + lrow][352 + lgr * 8];
        #pragma unroll
        for (int mf = 0; mf < 2; ++mf)
          #pragma unroll
          for (int nf = 0; nf < 4; ++nf)
            acc[mf][nf] = __builtin_amdgcn_mfma_f32_16x16x32_bf16(af[mf], bfr[nf], acc[mf][nf], 0, 0, 0);
      }

      float s[4] = {0.f, 0.f, 0.f, 0.f};
      const int rg = lgr * 4;
      #pragma unroll
      for (int mf = 0; mf < 2; ++mf) {
        #pragma unroll
        for (int reg = 0; reg < 4; ++reg) {
          const int q  = mbase + mf * 16 + rg + reg;  // 0..255
          const int qa = q >> 4, qb = q & 15;
          #pragma unroll
          for (int nf = 0; nf < 4; ++nf) {
            const int p = nf * 16 + lrow;
            s[nf] += acc[mf][nf][reg] * (sh.o0.x[qa][p] * sh.o0.x[qb][p]);
          }
        }
      }
      #pragma unroll
      for (int nf = 0; nf < 4; ++nf) {
        s[nf] += __shfl_xor(s[nf], 16);
        s[nf] += __shfl_xor(s[nf], 32);
      }
      if (lane < 16) {
        #pragma unroll
        for (int nf = 0; nf < 4; ++nf) sh.o0.red[wv][nf * 16 + lane] = s[nf];
      }
    }
    __syncthreads();

    if (tid < 64) {
      const int n  = tid;
      const int cc = ((pblk & 1) << 6) + n;
      float v = 0.f;
      #pragma unroll
      for (int k = 0; k < 8; ++k) v += sh.o0.red[k][n];
      float u1 = 0.f;
      #pragma unroll
      for (int xx = 0; xx < 16; ++xx) u1 += U1_0e[xx] * sh.o0.x[xx][n];
      out[(size_t)b * 512 + cc] = v + sh.o0.z[27][n] * u1;
    }
  }
}

extern "C" void kernel_launch(void* const* d_in, const int* in_sizes, int n_in,
                              void* d_out, int out_size, void* d_ws, size_t ws_size,
                              hipStream_t stream) {
  const float* x     = (const float*)d_in[0];
  const float* y     = (const float*)d_in[1];
  const float* U1_0e = (const float*)d_in[2];
  const float* U2_0e = (const float*)d_in[3];
  const float* U3_0e = (const float*)d_in[4];
  const float* U1_1o = (const float*)d_in[5];
  const float* U2_1o = (const float*)d_in[6];
  const float* U3_1o = (const float*)d_in[7];
  const float* w1_0e = (const float*)d_in[8];
  const float* w2_0e = (const float*)d_in[9];
  const float* w3_0e = (const float*)d_in[10];
  const float* w1_1o = (const float*)d_in[11];
  const float* w2_1o = (const float*)d_in[12];
  const float* w3_1o = (const float*)d_in[13];
  (void)in_sizes; (void)n_in; (void)out_size; (void)d_ws; (void)ws_size;

  hipLaunchKernelGGL(symcon_mfma, dim3(512), dim3(768), 0, stream,
                     x, y, U1_0e, U2_0e, U3_0e, U1_1o, U2_1o, U3_1o,
                     w1_0e, w2_0e, w3_0e, w1_1o, w2_1o, w3_1o,
                     (float*)d_out);
}